// Round 6
// baseline (5810.371 us; speedup 1.0000x reference)
//
#include <hip/hip_runtime.h>
#include <math.h>

namespace {

constexpr int Bb = 1024;
constexpr int Tn = 64;
constexpr int Dn = 8;
constexpr int Hn = 64;
constexpr int Wn = 128;
constexpr int BT = 2;    // batch rows per block (halved: grid 512 -> 2 blocks/CU)
constexpr int NT = 512;  // threads per block
constexpr int W1S = 68;  // w1s row stride: rows 4 banks apart -> 2-way max (free)
constexpr int YS  = 72;  // y/ys row stride: rows 8 banks apart (free for b128)
constexpr int HS  = 136; // h1/h2 row stride: same property
constexpr int KS  = 68;  // K_l inner stride
constexpr int W3F = 48;  // w3 front floats register-resident
constexpr int NCH = (Wn - W3F) / 4;   // 20 streamed float4 chunks (k=48..127)

// Tsit5 tableau
constexpr float A21 = 0.161f;
constexpr float A31 = -0.008480655492356989f, A32 = 0.335480655492357f;
constexpr float A41 = 2.8971530571054935f, A42 = -6.359448489975075f, A43 = 4.3622954328695815f;
constexpr float A51 = 5.325864828439257f, A52 = -11.748883564062828f, A53 = 7.4955393428898365f, A54 = -0.09249506636175525f;
constexpr float A61 = 5.86145544294642f, A62 = -12.92096931784711f, A63 = 8.159367898576159f, A64 = -0.071584973281401f, A65 = -0.028269050394068383f;
constexpr float Bc1 = 0.09646076681806523f, Bc2 = 0.01f, Bc3 = 0.4798896504144996f;
constexpr float Bc4 = 1.379008574103742f, Bc5 = -3.290069515436081f, Bc6 = 2.324710524099774f;

// fast transcendentals (v_exp/v_log/v_rcp based)
__device__ inline float fast_softplus(float x) {
  const float e = __expf(-fabsf(x));           // e in (0,1]
  return fmaxf(x, 0.f) + __logf(1.f + e);      // 1+e in [1,2]
}
__device__ inline float fast_tanh(float x) {
  const float xc = fminf(fmaxf(x, -10.f), 10.f);
  const float e2 = __expf(2.f * xc);
  return 1.f - __fdividef(2.f, e2 + 1.f);
}
__device__ inline float fast_sigmoid(float z) {
  return __fdividef(1.f, 1.f + __expf(-z));
}
__device__ inline float dot4(float4 w, float4 a) {
  return w.x * a.x + w.y * a.y + w.z * a.z + w.w * a.w;
}

} // namespace

// Persistent per-batch-tile NeuralCDE integrator.
//
// R6 vs R5 (2968us, VALUBusy 47%, Occupancy 24% = 2 waves/SIMD, stalls 53%):
// occupancy was LDS-blocked (124KB of weights -> 1 block/CU, grid 256).
// Now: BT=2, grid=512, LDS ~45KB -> 2 blocks/CU -> 4 waves/SIMD.
//  * w2 -> REGISTERS, quad k-split: thread (g2=tid&3, o=tid>>2) holds
//    w2[o][g2*32..+32) (32 VGPRs), computes partials for both batches,
//    2 shfl_xors reduce. Zero LDS for w2.
//  * w1 stays LDS (34.8KB), quad k-split reads (4 b128/thread/stage).
//  * w3: front 48k in regs, back 80k streamed from L2 (L2-hot, 4-buffer
//    rotating pipeline, refill distance ~3 iters). Opaque base pointer per
//    stage stops LICM from hoisting 80 floats into regs (would spill).
//  * __launch_bounds__(512,4): 4 waves/EU -> 128-VGPR cap, matches design
//    (~118 peak). waves_per_eu attribute REMOVED (could cap occupancy at 2).
__global__ __launch_bounds__(NT, 4)
void ncde_kernel(const float* __restrict__ xs,
                 const float* __restrict__ iw1, const float* __restrict__ ib1,
                 const float* __restrict__ iw2, const float* __restrict__ ib2,
                 const float* __restrict__ iw3, const float* __restrict__ ib3,
                 const float* __restrict__ vw1, const float* __restrict__ vb1,
                 const float* __restrict__ vw2, const float* __restrict__ vb2,
                 const float* __restrict__ vw3, const float* __restrict__ vb3,
                 const float* __restrict__ lw,  const float* __restrict__ lb,
                 float* __restrict__ out)
{
  __shared__ float w1s[Wn][W1S];          // 34.8 KB: w1s[o][k] row-major
  __shared__ float xs_l[BT][Tn * Dn];     // 4 KB control path
  __shared__ float y_l[BT][YS];           // current state
  __shared__ float ys_l[BT][YS];          // stage input
  __shared__ float K_l[6][BT][KS];        // stage slopes
  __shared__ float h1_l[BT][HS];
  __shared__ float h2_l[BT][HS];
  __shared__ float lw_l[Hn];

  const int tid = threadIdx.x;
  const int g2  = tid & 3;        // L1/L2 k-group (lane bits 0-1)
  const int o   = tid >> 2;       // L1/L2 output neuron, 0..127
  const int d   = tid & 7;        // L3 data-dim (row tid = h3*8+d)
  const int h3  = tid >> 3;       // L3 hidden index, 0..63
  const int b0  = blockIdx.x * BT;

  // ---- w2 quarter-row -> registers (one-time) ----
  float w2q[32];
  {
    const float4* p = (const float4*)(vw2 + o * Wn + g2 * 32);
    #pragma unroll
    for (int i = 0; i < 8; ++i) {
      float4 v = p[i];
      w2q[4*i+0] = v.x; w2q[4*i+1] = v.y; w2q[4*i+2] = v.z; w2q[4*i+3] = v.w;
    }
  }
  // ---- vw3 row tid, front 48 k -> registers (one-time) ----
  float w3r[W3F];
  {
    const float4* p = (const float4*)(vw3 + tid * Wn);
    #pragma unroll
    for (int i = 0; i < W3F / 4; ++i) {
      float4 v = p[i];
      w3r[4*i+0] = v.x; w3r[4*i+1] = v.y; w3r[4*i+2] = v.z; w3r[4*i+3] = v.w;
    }
  }
  const float b1r = vb1[o];
  const float b2r = vb2[o];
  const float b3r = vb3[tid];
  const float lb0 = lb[0];

  // ---- stage w1 row-major into LDS ----
  #pragma unroll
  for (int i = 0; i < 16; ++i) {          // 8192 f32 / 512 threads
    const int e = i * NT + tid;           // e = o*64 + k
    w1s[e >> 6][e & 63] = vw1[e];
  }
  // ---- this block's xs rows (256 x float4 = 4 KB) ----
  if (tid < 256)
    ((float4*)&xs_l[0][0])[tid] = ((const float4*)(xs + b0 * Tn * Dn))[tid];
  if (tid < Hn) lw_l[tid] = lw[tid];
  __syncthreads();

  // ---- initial MLP (relu, relu, identity): y0 = mlp(xs[:,0]) ----
  if (tid < BT * Wn) {
    const int b = tid >> 7, oo = tid & 127;
    float acc = ib1[oo];
    #pragma unroll
    for (int k = 0; k < Dn; ++k) acc += iw1[oo * Dn + k] * xs_l[b][k];
    h1_l[b][oo] = fmaxf(acc, 0.f);
  }
  __syncthreads();
  if (tid < BT * Wn) {
    const int b = tid >> 7, oo = tid & 127;
    float acc = ib2[oo];
    const float4* wrow = (const float4*)(iw2 + oo * Wn);
    #pragma unroll
    for (int k4 = 0; k4 < Wn / 4; ++k4)
      acc += dot4(wrow[k4], *(const float4*)&h1_l[b][k4 * 4]);
    h2_l[b][oo] = fmaxf(acc, 0.f);
  }
  __syncthreads();
  if (tid < BT * Hn) {
    const int b = tid >> 6, h = tid & (Hn - 1);
    float acc = ib3[h];
    const float4* wrow = (const float4*)(iw3 + h * Wn);
    #pragma unroll
    for (int k4 = 0; k4 < Wn / 4; ++k4)
      acc += dot4(wrow[k4], *(const float4*)&h2_l[b][k4 * 4]);
    y_l[b][h]  = acc;
    ys_l[b][h] = acc;
  }
  __syncthreads();

  auto readout = [&](int t) {
    if (tid < BT * Hn) {
      const int wv = tid >> 6, h = tid & (Hn - 1);
      float p = lw_l[h] * y_l[wv][h];
      #pragma unroll
      for (int off = 32; off > 0; off >>= 1) p += __shfl_xor(p, off, 64);
      if (h == 0) out[(b0 + wv) * Tn + t] = fast_sigmoid(p + lb0);
    }
  };
  readout(0);

  const float* vp_base = vw3 + tid * Wn + W3F;  // my row's streamed tail

  // ---- 63 Tsit5 steps; per stage: L1 -> bar -> L2 -> bar -> L3+update -> bar
  #pragma unroll 1
  for (int t = 0; t < Tn - 1; ++t) {
    float dxr[BT];

    #pragma unroll 1
    for (int s = 0; s < 6; ++s) {
      // streamed w3 tail: opaque base (no LICM), 4 chunks issued EARLY so
      // L2 latency hides under L1+L2 compute; refills pipelined in L3.
      const float* vp = vp_base;
      asm volatile("" : "+v"(vp));
      const float4* vp4 = (const float4*)vp;
      float4 ws0 = vp4[0], ws1 = vp4[1], ws2 = vp4[2], ws3 = vp4[3];

      if (s == 0) {
        #pragma unroll
        for (int b = 0; b < BT; ++b)
          dxr[b] = xs_l[b][(t + 1) * Dn + d] - xs_l[b][t * Dn + d];
      }

      // ---- vf layer 1: quad k-split (k = g2*16..+16), w1 from LDS ----
      {
        float a0 = 0.f, a1 = 0.f;
        #pragma unroll
        for (int j4 = 0; j4 < 4; ++j4) {
          const float4 wv = *(const float4*)&w1s[o][g2 * 16 + j4 * 4];
          a0 += dot4(wv, *(const float4*)&ys_l[0][g2 * 16 + j4 * 4]);
          a1 += dot4(wv, *(const float4*)&ys_l[1][g2 * 16 + j4 * 4]);
        }
        a0 += __shfl_xor(a0, 1, 64); a0 += __shfl_xor(a0, 2, 64);
        a1 += __shfl_xor(a1, 1, 64); a1 += __shfl_xor(a1, 2, 64);
        if (g2 < BT)
          h1_l[g2][o] = fast_softplus(((g2 == 0) ? a0 : a1) + b1r);
      }
      __syncthreads();
      // ---- vf layer 2: quad k-split (k = g2*32..+32), w2 from REGISTERS ----
      {
        float a0 = 0.f, a1 = 0.f;
        #pragma unroll
        for (int j4 = 0; j4 < 8; ++j4) {
          const float4 av0 = *(const float4*)&h1_l[0][g2 * 32 + j4 * 4];
          const float4 av1 = *(const float4*)&h1_l[1][g2 * 32 + j4 * 4];
          a0 += w2q[4*j4+0] * av0.x + w2q[4*j4+1] * av0.y
              + w2q[4*j4+2] * av0.z + w2q[4*j4+3] * av0.w;
          a1 += w2q[4*j4+0] * av1.x + w2q[4*j4+1] * av1.y
              + w2q[4*j4+2] * av1.z + w2q[4*j4+3] * av1.w;
        }
        a0 += __shfl_xor(a0, 1, 64); a0 += __shfl_xor(a0, 2, 64);
        a1 += __shfl_xor(a1, 1, 64); a1 += __shfl_xor(a1, 2, 64);
        if (g2 < BT)
          h2_l[g2][o] = fast_softplus(((g2 == 0) ? a0 : a1) + b2r);
      }
      __syncthreads();
      // ---- vf layer 3: row tid; front 48k regs + 80k streamed; fused update
      {
        float a0 = 0.f, a1 = 0.f;
        // front: k = 0..47 (uniform broadcast h2 reads)
        #pragma unroll
        for (int k4 = 0; k4 < W3F / 4; ++k4) {
          const float4 av0 = *(const float4*)&h2_l[0][k4 * 4];
          const float4 av1 = *(const float4*)&h2_l[1][k4 * 4];
          a0 += w3r[4*k4+0] * av0.x + w3r[4*k4+1] * av0.y
              + w3r[4*k4+2] * av0.z + w3r[4*k4+3] * av0.w;
          a1 += w3r[4*k4+0] * av1.x + w3r[4*k4+1] * av1.y
              + w3r[4*k4+2] * av1.z + w3r[4*k4+3] * av1.w;
        }
        // streamed: k = 48..127, 20 chunks through 4 rotating buffers
        #pragma unroll
        for (int c = 0; c < NCH; ++c) {
          float4 w;
          if ((c & 3) == 0) w = ws0;
          else if ((c & 3) == 1) w = ws1;
          else if ((c & 3) == 2) w = ws2;
          else w = ws3;
          a0 += dot4(w, *(const float4*)&h2_l[0][W3F + 4 * c]);
          a1 += dot4(w, *(const float4*)&h2_l[1][W3F + 4 * c]);
          if (c + 4 < NCH) {
            const float4 nw = vp4[c + 4];
            if ((c & 3) == 0) ws0 = nw;
            else if ((c & 3) == 1) ws1 = nw;
            else if ((c & 3) == 2) ws2 = nw;
            else ws3 = nw;
          }
        }
        // tanh + einsum over d (octet reduce)
        float p0 = fast_tanh(a0 + b3r) * dxr[0];
        float p1 = fast_tanh(a1 + b3r) * dxr[1];
        p0 += __shfl_xor(p0, 1, 64); p0 += __shfl_xor(p0, 2, 64); p0 += __shfl_xor(p0, 4, 64);
        p1 += __shfl_xor(p1, 1, 64); p1 += __shfl_xor(p1, 2, 64); p1 += __shfl_xor(p1, 4, 64);
        // fused tableau update: lane d<2 owns batch d (own-h3 data only)
        if (d < BT) {
          const float kv = (d == 0) ? p0 : p1;
          K_l[s][d][h3] = kv;
          float v = y_l[d][h3];
          if (s == 0)      v += A21 * kv;
          else if (s == 1) v += A31 * K_l[0][d][h3] + A32 * kv;
          else if (s == 2) v += A41 * K_l[0][d][h3] + A42 * K_l[1][d][h3] + A43 * kv;
          else if (s == 3) v += A51 * K_l[0][d][h3] + A52 * K_l[1][d][h3]
                              + A53 * K_l[2][d][h3] + A54 * kv;
          else if (s == 4) v += A61 * K_l[0][d][h3] + A62 * K_l[1][d][h3]
                              + A63 * K_l[2][d][h3] + A64 * K_l[3][d][h3] + A65 * kv;
          else             v += Bc1 * K_l[0][d][h3] + Bc2 * K_l[1][d][h3]
                              + Bc3 * K_l[2][d][h3] + Bc4 * K_l[3][d][h3]
                              + Bc5 * K_l[4][d][h3] + Bc6 * kv;
          if (s < 5) {
            ys_l[d][h3] = v;
          } else {
            y_l[d][h3]  = v;
            ys_l[d][h3] = v;
          }
        }
      }
      __syncthreads();
    }
    readout(t + 1);
  }
}

extern "C" void kernel_launch(void* const* d_in, const int* in_sizes, int n_in,
                              void* d_out, int out_size, void* d_ws, size_t ws_size,
                              hipStream_t stream) {
  const float* xs  = (const float*)d_in[1];
  const float* iw1 = (const float*)d_in[2];
  const float* ib1 = (const float*)d_in[3];
  const float* iw2 = (const float*)d_in[4];
  const float* ib2 = (const float*)d_in[5];
  const float* iw3 = (const float*)d_in[6];
  const float* ib3 = (const float*)d_in[7];
  const float* vw1 = (const float*)d_in[8];
  const float* vb1 = (const float*)d_in[9];
  const float* vw2 = (const float*)d_in[10];
  const float* vb2 = (const float*)d_in[11];
  const float* vw3 = (const float*)d_in[12];
  const float* vb3 = (const float*)d_in[13];
  const float* lw  = (const float*)d_in[14];
  const float* lb  = (const float*)d_in[15];
  float* out = (float*)d_out;

  ncde_kernel<<<Bb / BT, NT, 0, stream>>>(xs, iw1, ib1, iw2, ib2, iw3, ib3,
                                          vw1, vb1, vw2, vb2, vw3, vb3, lw, lb, out);
}

// Round 7
// 4402.951 us; speedup vs baseline: 1.3197x; 1.3197x over previous
//
#include <hip/hip_runtime.h>
#include <math.h>

namespace {

constexpr int Bb = 1024;
constexpr int Tn = 64;
constexpr int Dn = 8;
constexpr int Hn = 64;
constexpr int Wn = 128;
constexpr int BT = 4;     // batch rows per block
constexpr int NT = 1024;  // threads per block: 16 waves, 4 waves/SIMD resident
constexpr int W1S = 68;   // w1s row stride (floats)
constexpr int YS  = 72;   // y/ys row stride: rows 8 banks apart
constexpr int HS  = 136;  // h1/h2 row stride
constexpr int KS  = 68;   // K_l inner stride

// Tsit5 tableau
constexpr float A21 = 0.161f;
constexpr float A31 = -0.008480655492356989f, A32 = 0.335480655492357f;
constexpr float A41 = 2.8971530571054935f, A42 = -6.359448489975075f, A43 = 4.3622954328695815f;
constexpr float A51 = 5.325864828439257f, A52 = -11.748883564062828f, A53 = 7.4955393428898365f, A54 = -0.09249506636175525f;
constexpr float A61 = 5.86145544294642f, A62 = -12.92096931784711f, A63 = 8.159367898576159f, A64 = -0.071584973281401f, A65 = -0.028269050394068383f;
constexpr float Bc1 = 0.09646076681806523f, Bc2 = 0.01f, Bc3 = 0.4798896504144996f;
constexpr float Bc4 = 1.379008574103742f, Bc5 = -3.290069515436081f, Bc6 = 2.324710524099774f;

// fast transcendentals (v_exp/v_log/v_rcp based)
__device__ inline float fast_softplus(float x) {
  const float e = __expf(-fabsf(x));           // e in (0,1]
  return fmaxf(x, 0.f) + __logf(1.f + e);      // 1+e in [1,2]
}
__device__ inline float fast_tanh(float x) {
  const float xc = fminf(fmaxf(x, -10.f), 10.f);
  const float e2 = __expf(2.f * xc);
  return 1.f - __fdividef(2.f, e2 + 1.f);
}
__device__ inline float fast_sigmoid(float z) {
  return __fdividef(1.f, 1.f + __expf(-z));
}
__device__ inline float dot4(float4 w, float4 a) {
  return w.x * a.x + w.y * a.y + w.z * a.z + w.w * a.w;
}

} // namespace

// Persistent per-batch-tile NeuralCDE integrator, 1024 threads/block.
//
// R7 = R6's occupancy (4 waves/SIMD, proven reachable) + R5's no-spill
// discipline, designed to fit the 64-VGPR cap the allocator always picks:
//  * w2 -> regs, 16 floats/thread: thread (g3=tid&7, o=tid>>3) holds
//    k-chunks {g3*4+32m : m=0..3}. INTERLEAVED chunks put the 8 octet
//    lanes' activation reads on 8 distinct bank-quads (conflict-free).
//  * w1 -> LDS (34.8 KB, total LDS ~56 KB; 1 block/CU is grid-forced).
//  * w3 -> fully streamed from L2: per-lane base vw3 + tid*64 floats =
//    contiguous 256B/lane (perfect coalescing); 16 float4 chunks through
//    a 4-deep rotation (prefetch distance ~256 cyc > 200 cyc L2 latency).
//  * L3: thread pair (row=tid>>1, hf=tid&1) splits k 0..63/64..127;
//    xor(1) joins halves, xor(2/4/8) does the einsum d-reduce.
// Register tally: 16 w2q + 16 stream + 4 acc + 4 dxr + 4 scalars + 2 addr
// + ~14 transients ~= 60 < 64. Tripwire: FETCH_SIZE >= 1e5 KB => spilled.
__global__ __launch_bounds__(NT, 4)
void ncde_kernel(const float* __restrict__ xs,
                 const float* __restrict__ iw1, const float* __restrict__ ib1,
                 const float* __restrict__ iw2, const float* __restrict__ ib2,
                 const float* __restrict__ iw3, const float* __restrict__ ib3,
                 const float* __restrict__ vw1, const float* __restrict__ vb1,
                 const float* __restrict__ vw2, const float* __restrict__ vb2,
                 const float* __restrict__ vw3, const float* __restrict__ vb3,
                 const float* __restrict__ lw,  const float* __restrict__ lb,
                 float* __restrict__ out)
{
  __shared__ float w1s[Wn][W1S];          // 34.8 KB: w1s[o][k] row-major
  __shared__ float xs_l[BT][Tn * Dn];     // 8 KB control path
  __shared__ float y_l[BT][YS];           // current state
  __shared__ float ys_l[BT][YS];          // stage input
  __shared__ float K_l[6][BT][KS];        // stage slopes
  __shared__ float h1_l[BT][HS];
  __shared__ float h2_l[BT][HS];
  __shared__ float lw_l[Hn];

  const int tid = threadIdx.x;
  const int g3  = tid & 7;        // L1/L2 k-octet lane
  const int o8  = tid >> 3;       // L1/L2 output neuron, 0..127
  const int row = tid >> 1;       // L3 vw3 row, 0..511
  const int hf  = tid & 1;        // L3 k-half
  const int d   = (tid >> 1) & 7; // L3 data-dim (row = h3*8 + d)
  const int h3  = tid >> 4;       // L3 hidden index, 0..63
  const int b0  = blockIdx.x * BT;

  // ---- w2 sixteenth-row -> regs: w2q4[m] = vw2[o8*128 + 32m + 4g3 ..+4) ----
  float4 w2q4[4];
  #pragma unroll
  for (int m = 0; m < 4; ++m)
    w2q4[m] = ((const float4*)vw2)[o8 * 32 + m * 8 + g3];

  const float b1r = vb1[o8];
  const float b2r = vb2[o8];
  const float b3r = vb3[row];
  const float lb0 = lb[0];

  // ---- stage w1 row-major into LDS ----
  #pragma unroll
  for (int i = 0; i < 8; ++i) {           // 8192 f32 / 1024 threads
    const int e = i * NT + tid;           // e = o*64 + k
    w1s[e >> 6][e & 63] = vw1[e];
  }
  // ---- this block's xs rows (512 x float4 = 8 KB) ----
  if (tid < 512)
    ((float4*)&xs_l[0][0])[tid] = ((const float4*)(xs + b0 * Tn * Dn))[tid];
  if (tid < Hn) lw_l[tid] = lw[tid];
  __syncthreads();

  // ---- initial MLP (relu, relu, identity): y0 = mlp(xs[:,0]) ----
  if (tid < 512) {
    const int b = tid >> 7, oo = tid & 127;
    float acc = ib1[oo];
    #pragma unroll
    for (int k = 0; k < Dn; ++k) acc += iw1[oo * Dn + k] * xs_l[b][k];
    h1_l[b][oo] = fmaxf(acc, 0.f);
  }
  __syncthreads();
  if (tid < 512) {
    const int b = tid >> 7, oo = tid & 127;
    float acc = ib2[oo];
    const float4* wrow = (const float4*)(iw2 + oo * Wn);
    #pragma unroll
    for (int k4 = 0; k4 < Wn / 4; ++k4)
      acc += dot4(wrow[k4], *(const float4*)&h1_l[b][k4 * 4]);
    h2_l[b][oo] = fmaxf(acc, 0.f);
  }
  __syncthreads();
  if (tid < BT * Hn) {
    const int b = tid >> 6, h = tid & (Hn - 1);
    float acc = ib3[h];
    const float4* wrow = (const float4*)(iw3 + h * Wn);
    #pragma unroll
    for (int k4 = 0; k4 < Wn / 4; ++k4)
      acc += dot4(wrow[k4], *(const float4*)&h2_l[b][k4 * 4]);
    y_l[b][h]  = acc;
    ys_l[b][h] = acc;
  }
  __syncthreads();

  auto readout = [&](int t) {
    if (tid < BT * Hn) {
      const int wv = tid >> 6, h = tid & (Hn - 1);
      float p = lw_l[h] * y_l[wv][h];
      #pragma unroll
      for (int off = 32; off > 0; off >>= 1) p += __shfl_xor(p, off, 64);
      if (h == 0) out[(b0 + wv) * Tn + t] = fast_sigmoid(p + lb0);
    }
  };
  readout(0);

  // per-lane contiguous 256B: row*128 + hf*64 == tid*64
  const float* vp_base = vw3 + tid * 64;

  // ---- 63 Tsit5 steps; per stage: L1 -> bar -> L2 -> bar -> L3+update -> bar
  #pragma unroll 1
  for (int t = 0; t < Tn - 1; ++t) {
    float dxr[BT];

    #pragma unroll 1
    for (int s = 0; s < 6; ++s) {
      // streamed w3: opaque base (no LICM -> no spill); 4 chunks in flight
      // from stage start so L2 latency hides under L1+L2 compute.
      const float* vp = vp_base;
      asm volatile("" : "+v"(vp));
      const float4* vp4 = (const float4*)vp;
      float4 ws0 = vp4[0], ws1 = vp4[1], ws2 = vp4[2], ws3 = vp4[3];

      if (s == 0) {
        #pragma unroll
        for (int b = 0; b < BT; ++b)
          dxr[b] = xs_l[b][(t + 1) * Dn + d] - xs_l[b][t * Dn + d];
      }

      // ---- vf layer 1: octet k-split, interleaved chunks {g3*4+32m} ----
      {
        float a0 = 0.f, a1 = 0.f, a2 = 0.f, a3 = 0.f;
        #pragma unroll
        for (int m = 0; m < 2; ++m) {
          const int kk = g3 * 4 + 32 * m;
          const float4 wv = *(const float4*)&w1s[o8][kk];
          a0 += dot4(wv, *(const float4*)&ys_l[0][kk]);
          a1 += dot4(wv, *(const float4*)&ys_l[1][kk]);
          a2 += dot4(wv, *(const float4*)&ys_l[2][kk]);
          a3 += dot4(wv, *(const float4*)&ys_l[3][kk]);
        }
        a0 += __shfl_xor(a0, 1, 64); a0 += __shfl_xor(a0, 2, 64); a0 += __shfl_xor(a0, 4, 64);
        a1 += __shfl_xor(a1, 1, 64); a1 += __shfl_xor(a1, 2, 64); a1 += __shfl_xor(a1, 4, 64);
        a2 += __shfl_xor(a2, 1, 64); a2 += __shfl_xor(a2, 2, 64); a2 += __shfl_xor(a2, 4, 64);
        a3 += __shfl_xor(a3, 1, 64); a3 += __shfl_xor(a3, 2, 64); a3 += __shfl_xor(a3, 4, 64);
        if (g3 < BT) {
          const float v = (g3 == 0) ? a0 : (g3 == 1) ? a1 : (g3 == 2) ? a2 : a3;
          h1_l[g3][o8] = fast_softplus(v + b1r);
        }
      }
      __syncthreads();
      // ---- vf layer 2: octet k-split, w2 from REGISTERS ----
      {
        float a0 = 0.f, a1 = 0.f, a2 = 0.f, a3 = 0.f;
        #pragma unroll
        for (int m = 0; m < 4; ++m) {
          const int kk = g3 * 4 + 32 * m;
          a0 += dot4(w2q4[m], *(const float4*)&h1_l[0][kk]);
          a1 += dot4(w2q4[m], *(const float4*)&h1_l[1][kk]);
          a2 += dot4(w2q4[m], *(const float4*)&h1_l[2][kk]);
          a3 += dot4(w2q4[m], *(const float4*)&h1_l[3][kk]);
        }
        a0 += __shfl_xor(a0, 1, 64); a0 += __shfl_xor(a0, 2, 64); a0 += __shfl_xor(a0, 4, 64);
        a1 += __shfl_xor(a1, 1, 64); a1 += __shfl_xor(a1, 2, 64); a1 += __shfl_xor(a1, 4, 64);
        a2 += __shfl_xor(a2, 1, 64); a2 += __shfl_xor(a2, 2, 64); a2 += __shfl_xor(a2, 4, 64);
        a3 += __shfl_xor(a3, 1, 64); a3 += __shfl_xor(a3, 2, 64); a3 += __shfl_xor(a3, 4, 64);
        if (g3 < BT) {
          const float v = (g3 == 0) ? a0 : (g3 == 1) ? a1 : (g3 == 2) ? a2 : a3;
          h2_l[g3][o8] = fast_softplus(v + b2r);
        }
      }
      __syncthreads();
      // ---- vf layer 3: pair k-split (hf), streamed w3, fused update ----
      {
        float a0 = 0.f, a1 = 0.f, a2 = 0.f, a3 = 0.f;
        const int kb = hf << 6;
        #pragma unroll
        for (int c = 0; c < 16; ++c) {
          float4 w;
          if ((c & 3) == 0) w = ws0;
          else if ((c & 3) == 1) w = ws1;
          else if ((c & 3) == 2) w = ws2;
          else w = ws3;
          const int kk = kb + c * 4;
          a0 += dot4(w, *(const float4*)&h2_l[0][kk]);
          a1 += dot4(w, *(const float4*)&h2_l[1][kk]);
          a2 += dot4(w, *(const float4*)&h2_l[2][kk]);
          a3 += dot4(w, *(const float4*)&h2_l[3][kk]);
          if (c + 4 < 16) {
            const float4 nw = vp4[c + 4];
            if ((c & 3) == 0) ws0 = nw;
            else if ((c & 3) == 1) ws1 = nw;
            else if ((c & 3) == 2) ws2 = nw;
            else ws3 = nw;
          }
        }
        // join k-halves, tanh, einsum over d
        a0 += __shfl_xor(a0, 1, 64);
        a1 += __shfl_xor(a1, 1, 64);
        a2 += __shfl_xor(a2, 1, 64);
        a3 += __shfl_xor(a3, 1, 64);
        float p0 = fast_tanh(a0 + b3r) * dxr[0];
        float p1 = fast_tanh(a1 + b3r) * dxr[1];
        float p2 = fast_tanh(a2 + b3r) * dxr[2];
        float p3 = fast_tanh(a3 + b3r) * dxr[3];
        p0 += __shfl_xor(p0, 2, 64); p0 += __shfl_xor(p0, 4, 64); p0 += __shfl_xor(p0, 8, 64);
        p1 += __shfl_xor(p1, 2, 64); p1 += __shfl_xor(p1, 4, 64); p1 += __shfl_xor(p1, 8, 64);
        p2 += __shfl_xor(p2, 2, 64); p2 += __shfl_xor(p2, 4, 64); p2 += __shfl_xor(p2, 8, 64);
        p3 += __shfl_xor(p3, 2, 64); p3 += __shfl_xor(p3, 4, 64); p3 += __shfl_xor(p3, 8, 64);
        const int wl = tid & 15;
        if (wl < BT) {
          const float kv = (wl == 0) ? p0 : (wl == 1) ? p1 : (wl == 2) ? p2 : p3;
          K_l[s][wl][h3] = kv;
          float v = y_l[wl][h3];
          if (s == 0)      v += A21 * kv;
          else if (s == 1) v += A31 * K_l[0][wl][h3] + A32 * kv;
          else if (s == 2) v += A41 * K_l[0][wl][h3] + A42 * K_l[1][wl][h3] + A43 * kv;
          else if (s == 3) v += A51 * K_l[0][wl][h3] + A52 * K_l[1][wl][h3]
                              + A53 * K_l[2][wl][h3] + A54 * kv;
          else if (s == 4) v += A61 * K_l[0][wl][h3] + A62 * K_l[1][wl][h3]
                              + A63 * K_l[2][wl][h3] + A64 * K_l[3][wl][h3] + A65 * kv;
          else             v += Bc1 * K_l[0][wl][h3] + Bc2 * K_l[1][wl][h3]
                              + Bc3 * K_l[2][wl][h3] + Bc4 * K_l[3][wl][h3]
                              + Bc5 * K_l[4][wl][h3] + Bc6 * kv;
          if (s < 5) {
            ys_l[wl][h3] = v;
          } else {
            y_l[wl][h3]  = v;
            ys_l[wl][h3] = v;
          }
        }
      }
      __syncthreads();
    }
    readout(t + 1);
  }
}

extern "C" void kernel_launch(void* const* d_in, const int* in_sizes, int n_in,
                              void* d_out, int out_size, void* d_ws, size_t ws_size,
                              hipStream_t stream) {
  const float* xs  = (const float*)d_in[1];
  const float* iw1 = (const float*)d_in[2];
  const float* ib1 = (const float*)d_in[3];
  const float* iw2 = (const float*)d_in[4];
  const float* ib2 = (const float*)d_in[5];
  const float* iw3 = (const float*)d_in[6];
  const float* ib3 = (const float*)d_in[7];
  const float* vw1 = (const float*)d_in[8];
  const float* vb1 = (const float*)d_in[9];
  const float* vw2 = (const float*)d_in[10];
  const float* vb2 = (const float*)d_in[11];
  const float* vw3 = (const float*)d_in[12];
  const float* vb3 = (const float*)d_in[13];
  const float* lw  = (const float*)d_in[14];
  const float* lb  = (const float*)d_in[15];
  float* out = (float*)d_out;

  ncde_kernel<<<Bb / BT, NT, 0, stream>>>(xs, iw1, ib1, iw2, ib2, iw3, ib3,
                                          vw1, vb1, vw2, vb2, vw3, vb3, lw, lb, out);
}

// Round 8
// 3563.712 us; speedup vs baseline: 1.6304x; 1.2355x over previous
//
#include <hip/hip_runtime.h>
#include <math.h>

namespace {

constexpr int Bb = 1024;
constexpr int Tn = 64;
constexpr int Dn = 8;
constexpr int Hn = 64;
constexpr int Wn = 128;
constexpr int BT = 4;     // batch rows per block
constexpr int NT = 1024;  // 16 waves, 4 waves/SIMD (1 block/CU, LDS-forced)
constexpr int W1S = 68;   // w1s row stride: banks (4o+4k) -> 2-way max (free)
constexpr int W2S = 132;  // w2s row stride: same property
constexpr int YS  = 72;   // y/ys row stride: rows 8 banks apart (b12-quad free)
constexpr int HS  = 136;  // h1/h2 row stride: same property
constexpr int KS  = 68;   // K_l inner stride

// Tsit5 tableau
constexpr float A21 = 0.161f;
constexpr float A31 = -0.008480655492356989f, A32 = 0.335480655492357f;
constexpr float A41 = 2.8971530571054935f, A42 = -6.359448489975075f, A43 = 4.3622954328695815f;
constexpr float A51 = 5.325864828439257f, A52 = -11.748883564062828f, A53 = 7.4955393428898365f, A54 = -0.09249506636175525f;
constexpr float A61 = 5.86145544294642f, A62 = -12.92096931784711f, A63 = 8.159367898576159f, A64 = -0.071584973281401f, A65 = -0.028269050394068383f;
constexpr float Bc1 = 0.09646076681806523f, Bc2 = 0.01f, Bc3 = 0.4798896504144996f;
constexpr float Bc4 = 1.379008574103742f, Bc5 = -3.290069515436081f, Bc6 = 2.324710524099774f;

// fast transcendentals (v_exp/v_log/v_rcp based)
__device__ inline float fast_softplus(float x) {
  const float e = __expf(-fabsf(x));           // e in (0,1]
  return fmaxf(x, 0.f) + __logf(1.f + e);      // 1+e in [1,2]
}
__device__ inline float fast_tanh(float x) {
  const float xc = fminf(fmaxf(x, -10.f), 10.f);
  const float e2 = __expf(2.f * xc);
  return 1.f - __fdividef(2.f, e2 + 1.f);
}
__device__ inline float fast_sigmoid(float z) {
  return __fdividef(1.f, 1.f + __expf(-z));
}
__device__ inline float dot4(float4 w, float4 a) {
  return w.x * a.x + w.y * a.y + w.z * a.z + w.w * a.w;
}

} // namespace

// Persistent per-batch-tile NeuralCDE integrator, 1024 threads/block.
//
// R8 = R7's occupancy (4 waves/SIMD, VGPR<=64, no spill) + R5's proven
// conflict-free LDS patterns (R7's octet k-split w1 reads were 8-way bank
// conflicts: 4.2e8 cycles ~= 0.7ms):
//  * w1 AND w2 in LDS (102 KB). L1/L2 computed by tid<512 with R5's exact
//    full-dot layout (b12=tid&3, o=tid>>2): weight reads are 16-row/
//    4-lane-broadcast (2-way max), activation reads 4-row-quad on distinct
//    bank-quads (free). Upper 8 waves idle at barrier during L1/L2 (they
//    consume no issue slots); all 16 waves run L3 (~70% of FLOPs).
//  * w3 fully streamed from L2 (256KB, XCD-hot): thread tid reads its
//    contiguous 256B (row=tid>>1, half=tid&1) via 8-deep rotation ->
//    prefetch distance ~256cyc > ~200cyc L2 latency. Opaque base pointer
//    per stage prevents LICM from hoisting the stream into regs (spill).
//  * fused tableau update + fast transcendentals as R5/R7.
// Register tally: 32 stream + 4 acc + 4 dxr + ~20 scalars/misc < 64.
__global__ __launch_bounds__(NT, 4)
void ncde_kernel(const float* __restrict__ xs,
                 const float* __restrict__ iw1, const float* __restrict__ ib1,
                 const float* __restrict__ iw2, const float* __restrict__ ib2,
                 const float* __restrict__ iw3, const float* __restrict__ ib3,
                 const float* __restrict__ vw1, const float* __restrict__ vb1,
                 const float* __restrict__ vw2, const float* __restrict__ vb2,
                 const float* __restrict__ vw3, const float* __restrict__ vb3,
                 const float* __restrict__ lw,  const float* __restrict__ lb,
                 float* __restrict__ out)
{
  __shared__ float w1s[Wn][W1S];          // 34.8 KB: w1s[o][k] row-major
  __shared__ float w2s[Wn][W2S];          // 67.6 KB: w2s[o][k] row-major
  __shared__ float xs_l[BT][Tn * Dn];     // 8 KB control path
  __shared__ float y_l[BT][YS];           // current state
  __shared__ float ys_l[BT][YS];          // stage input
  __shared__ float K_l[6][BT][KS];        // stage slopes
  __shared__ float h1_l[BT][HS];
  __shared__ float h2_l[BT][HS];
  __shared__ float lw_l[Hn];

  const int tid = threadIdx.x;
  const int b12 = tid & 3;        // L1/L2 batch row (tid<512)
  const int oL  = (tid >> 2) & 127; // L1/L2 output neuron (tid<512)
  const int hf  = tid & 1;        // L3 k-half
  const int d   = (tid >> 1) & 7; // L3 data-dim (vw3 row = tid>>1 = h3*8+d)
  const int h3  = tid >> 4;       // L3 hidden index, 0..63
  const int b0  = blockIdx.x * BT;

  const float b1r = vb1[oL];
  const float b2r = vb2[oL];
  const float b3r = vb3[tid >> 1];
  const float lb0 = lb[0];

  // ---- stage w1/w2 row-major into LDS ----
  #pragma unroll
  for (int i = 0; i < 8; ++i) {           // 8192 f32 / 1024 threads
    const int e = i * NT + tid;           // e = o*64 + k
    w1s[e >> 6][e & 63] = vw1[e];
  }
  #pragma unroll
  for (int i = 0; i < 16; ++i) {          // 16384 f32 / 1024 threads
    const int e = i * NT + tid;           // e = o*128 + k
    w2s[e >> 7][e & 127] = vw2[e];
  }
  // ---- this block's xs rows (512 x float4 = 8 KB) ----
  if (tid < 512)
    ((float4*)&xs_l[0][0])[tid] = ((const float4*)(xs + b0 * Tn * Dn))[tid];
  if (tid < Hn) lw_l[tid] = lw[tid];
  __syncthreads();

  // ---- initial MLP (relu, relu, identity): y0 = mlp(xs[:,0]) ----
  if (tid < 512) {
    const int b = tid >> 7, oo = tid & 127;
    float acc = ib1[oo];
    #pragma unroll
    for (int k = 0; k < Dn; ++k) acc += iw1[oo * Dn + k] * xs_l[b][k];
    h1_l[b][oo] = fmaxf(acc, 0.f);
  }
  __syncthreads();
  if (tid < 512) {
    const int b = tid >> 7, oo = tid & 127;
    float acc = ib2[oo];
    const float4* wrow = (const float4*)(iw2 + oo * Wn);
    #pragma unroll
    for (int k4 = 0; k4 < Wn / 4; ++k4)
      acc += dot4(wrow[k4], *(const float4*)&h1_l[b][k4 * 4]);
    h2_l[b][oo] = fmaxf(acc, 0.f);
  }
  __syncthreads();
  if (tid < BT * Hn) {
    const int b = tid >> 6, h = tid & (Hn - 1);
    float acc = ib3[h];
    const float4* wrow = (const float4*)(iw3 + h * Wn);
    #pragma unroll
    for (int k4 = 0; k4 < Wn / 4; ++k4)
      acc += dot4(wrow[k4], *(const float4*)&h2_l[b][k4 * 4]);
    y_l[b][h]  = acc;
    ys_l[b][h] = acc;
  }
  __syncthreads();

  auto readout = [&](int t) {
    if (tid < BT * Hn) {
      const int wv = tid >> 6, h = tid & (Hn - 1);
      float p = lw_l[h] * y_l[wv][h];
      #pragma unroll
      for (int off = 32; off > 0; off >>= 1) p += __shfl_xor(p, off, 64);
      if (h == 0) out[(b0 + wv) * Tn + t] = fast_sigmoid(p + lb0);
    }
  };
  readout(0);

  // per-lane contiguous 256B of vw3: row*128 + hf*64 == tid*64
  const float* vp_base = vw3 + tid * 64;

  // ---- 63 Tsit5 steps; per stage: L1 -> bar -> L2 -> bar -> L3+update -> bar
  #pragma unroll 1
  for (int t = 0; t < Tn - 1; ++t) {
    float dxr[BT];

    #pragma unroll 1
    for (int s = 0; s < 6; ++s) {
      // streamed w3: opaque base (no LICM -> no spill); 8 chunks in flight
      // from stage start so L2 latency hides under L1+L2 compute.
      const float* vp = vp_base;
      asm volatile("" : "+v"(vp));
      const float4* vp4 = (const float4*)vp;
      float4 ws[8];
      #pragma unroll
      for (int j = 0; j < 8; ++j) ws[j] = vp4[j];

      if (s == 0) {
        #pragma unroll
        for (int b = 0; b < BT; ++b)
          dxr[b] = xs_l[b][(t + 1) * Dn + d] - xs_l[b][t * Dn + d];
      }

      // ---- vf layer 1 (tid<512, R5 pattern): full 64-k dot ----
      if (tid < 512) {
        float acc = b1r;
        #pragma unroll
        for (int k4 = 0; k4 < 16; ++k4)
          acc += dot4(*(const float4*)&w1s[oL][k4 * 4],
                      *(const float4*)&ys_l[b12][k4 * 4]);
        h1_l[b12][oL] = fast_softplus(acc);
      }
      __syncthreads();
      // ---- vf layer 2 (tid<512, R5 pattern): full 128-k dot ----
      if (tid < 512) {
        float acc = b2r;
        #pragma unroll
        for (int k4 = 0; k4 < 32; ++k4)
          acc += dot4(*(const float4*)&w2s[oL][k4 * 4],
                      *(const float4*)&h1_l[b12][k4 * 4]);
        h2_l[b12][oL] = fast_softplus(acc);
      }
      __syncthreads();
      // ---- vf layer 3 (all 1024): pair k-split, streamed w3, fused update
      {
        float a0 = 0.f, a1 = 0.f, a2 = 0.f, a3 = 0.f;
        const int kb = hf << 6;
        // first 8 chunks: use ws[c], refill with vp4[8+c]
        #pragma unroll
        for (int c = 0; c < 8; ++c) {
          const int kk = kb + 4 * c;
          a0 += dot4(ws[c], *(const float4*)&h2_l[0][kk]);
          a1 += dot4(ws[c], *(const float4*)&h2_l[1][kk]);
          a2 += dot4(ws[c], *(const float4*)&h2_l[2][kk]);
          a3 += dot4(ws[c], *(const float4*)&h2_l[3][kk]);
          ws[c] = vp4[8 + c];
        }
        // last 8 chunks
        #pragma unroll
        for (int c = 0; c < 8; ++c) {
          const int kk = kb + 32 + 4 * c;
          a0 += dot4(ws[c], *(const float4*)&h2_l[0][kk]);
          a1 += dot4(ws[c], *(const float4*)&h2_l[1][kk]);
          a2 += dot4(ws[c], *(const float4*)&h2_l[2][kk]);
          a3 += dot4(ws[c], *(const float4*)&h2_l[3][kk]);
        }
        // join k-halves, tanh, einsum over d
        a0 += __shfl_xor(a0, 1, 64);
        a1 += __shfl_xor(a1, 1, 64);
        a2 += __shfl_xor(a2, 1, 64);
        a3 += __shfl_xor(a3, 1, 64);
        float p0 = fast_tanh(a0 + b3r) * dxr[0];
        float p1 = fast_tanh(a1 + b3r) * dxr[1];
        float p2 = fast_tanh(a2 + b3r) * dxr[2];
        float p3 = fast_tanh(a3 + b3r) * dxr[3];
        p0 += __shfl_xor(p0, 2, 64); p0 += __shfl_xor(p0, 4, 64); p0 += __shfl_xor(p0, 8, 64);
        p1 += __shfl_xor(p1, 2, 64); p1 += __shfl_xor(p1, 4, 64); p1 += __shfl_xor(p1, 8, 64);
        p2 += __shfl_xor(p2, 2, 64); p2 += __shfl_xor(p2, 4, 64); p2 += __shfl_xor(p2, 8, 64);
        p3 += __shfl_xor(p3, 2, 64); p3 += __shfl_xor(p3, 4, 64); p3 += __shfl_xor(p3, 8, 64);
        const int wl = tid & 15;
        if (wl < BT) {
          const float kv = (wl == 0) ? p0 : (wl == 1) ? p1 : (wl == 2) ? p2 : p3;
          K_l[s][wl][h3] = kv;
          float v = y_l[wl][h3];
          if (s == 0)      v += A21 * kv;
          else if (s == 1) v += A31 * K_l[0][wl][h3] + A32 * kv;
          else if (s == 2) v += A41 * K_l[0][wl][h3] + A42 * K_l[1][wl][h3] + A43 * kv;
          else if (s == 3) v += A51 * K_l[0][wl][h3] + A52 * K_l[1][wl][h3]
                              + A53 * K_l[2][wl][h3] + A54 * kv;
          else if (s == 4) v += A61 * K_l[0][wl][h3] + A62 * K_l[1][wl][h3]
                              + A63 * K_l[2][wl][h3] + A64 * K_l[3][wl][h3] + A65 * kv;
          else             v += Bc1 * K_l[0][wl][h3] + Bc2 * K_l[1][wl][h3]
                              + Bc3 * K_l[2][wl][h3] + Bc4 * K_l[3][wl][h3]
                              + Bc5 * K_l[4][wl][h3] + Bc6 * kv;
          if (s < 5) {
            ys_l[wl][h3] = v;
          } else {
            y_l[wl][h3]  = v;
            ys_l[wl][h3] = v;
          }
        }
      }
      __syncthreads();
    }
    readout(t + 1);
  }
}

extern "C" void kernel_launch(void* const* d_in, const int* in_sizes, int n_in,
                              void* d_out, int out_size, void* d_ws, size_t ws_size,
                              hipStream_t stream) {
  const float* xs  = (const float*)d_in[1];
  const float* iw1 = (const float*)d_in[2];
  const float* ib1 = (const float*)d_in[3];
  const float* iw2 = (const float*)d_in[4];
  const float* ib2 = (const float*)d_in[5];
  const float* iw3 = (const float*)d_in[6];
  const float* ib3 = (const float*)d_in[7];
  const float* vw1 = (const float*)d_in[8];
  const float* vb1 = (const float*)d_in[9];
  const float* vw2 = (const float*)d_in[10];
  const float* vb2 = (const float*)d_in[11];
  const float* vw3 = (const float*)d_in[12];
  const float* vb3 = (const float*)d_in[13];
  const float* lw  = (const float*)d_in[14];
  const float* lb  = (const float*)d_in[15];
  float* out = (float*)d_out;

  ncde_kernel<<<Bb / BT, NT, 0, stream>>>(xs, iw1, ib1, iw2, ib2, iw3, ib3,
                                          vw1, vb1, vw2, vb2, vw3, vb3, lw, lb, out);
}

// Round 9
// 2042.790 us; speedup vs baseline: 2.8443x; 1.7445x over previous
//
#include <hip/hip_runtime.h>
#include <math.h>

namespace {

constexpr int Bb = 1024;
constexpr int Tn = 64;
constexpr int Dn = 8;
constexpr int Hn = 64;
constexpr int Wn = 128;
constexpr int BT = 4;     // batch rows per block
constexpr int NT = 1024;  // 16 waves, 4 waves/SIMD, 1 block/CU
constexpr int W1S = 68;   // w1s row stride
constexpr int W2S = 132;  // w2s row stride
constexpr int YS  = 72;   // y/ys row stride: rows 8 banks apart
constexpr int HS  = 136;  // h1/h2 row stride; halves at phys 0 and 68:
                          // GAP trick -> L3's two wave-addresses (hf=0/1)
                          // land on disjoint bank-quads (single pass)
constexpr int GAP = 68;   // phys offset of k=64..127 half
constexpr int KS  = 68;   // K_l inner stride

// Tsit5 tableau
constexpr float A21 = 0.161f;
constexpr float A31 = -0.008480655492356989f, A32 = 0.335480655492357f;
constexpr float A41 = 2.8971530571054935f, A42 = -6.359448489975075f, A43 = 4.3622954328695815f;
constexpr float A51 = 5.325864828439257f, A52 = -11.748883564062828f, A53 = 7.4955393428898365f, A54 = -0.09249506636175525f;
constexpr float A61 = 5.86145544294642f, A62 = -12.92096931784711f, A63 = 8.159367898576159f, A64 = -0.071584973281401f, A65 = -0.028269050394068383f;
constexpr float Bc1 = 0.09646076681806523f, Bc2 = 0.01f, Bc3 = 0.4798896504144996f;
constexpr float Bc4 = 1.379008574103742f, Bc5 = -3.290069515436081f, Bc6 = 2.324710524099774f;

// fast transcendentals (v_exp/v_log/v_rcp based)
__device__ inline float fast_softplus(float x) {
  const float e = __expf(-fabsf(x));           // e in (0,1]
  return fmaxf(x, 0.f) + __logf(1.f + e);      // 1+e in [1,2]
}
__device__ inline float fast_tanh(float x) {
  const float xc = fminf(fmaxf(x, -10.f), 10.f);
  const float e2 = __expf(2.f * xc);
  return 1.f - __fdividef(2.f, e2 + 1.f);
}
__device__ inline float fast_sigmoid(float z) {
  return __fdividef(1.f, 1.f + __expf(-z));
}
__device__ inline float dot4(float4 w, float4 a) {
  return w.x * a.x + w.y * a.y + w.z * a.z + w.w * a.w;
}

} // namespace

// Persistent per-batch-tile NeuralCDE integrator, 1024 threads/block.
//
// R9 vs R8 (3564us, VALUBusy 43%, conflicts 3.96e8, VGPR 52/128 cap):
//  1. w3 REGISTER-RESIDENT (w3r[64], row=tid>>1, half=tid&1, loaded once).
//     R8 left 76 VGPRs idle while re-streaming w3 from L2 every stage
//     (16 loads + addressing + ~4.5k cyc/stage L2 bandwidth). Gone.
//  2. h1/h2 GAP layout: halves at phys 0 / 68. R7+R8's conflict source
//     was L3's hf-split h2 reads: two wave-addresses 256B apart = same
//     bank-quad -> double-pass on all 64 reads/thread/stage (=3.9e8 cyc).
//     With the gap the two addresses hit disjoint quads: single pass.
//  * L1/L2: R5's proven full-dot pattern (tid<512), gap-aware.
//  * fused tableau update, fast transcendentals, 3 barriers/stage as R8.
// Reg tally: 64 w3r + 4 acc + 4 dxr + ~25 misc ~= 97 < 128 cap (lb 1024,4).
// Tripwire: FETCH_SIZE >= 1e5 KB => w3r spilled.
__global__ __launch_bounds__(NT, 4)
void ncde_kernel(const float* __restrict__ xs,
                 const float* __restrict__ iw1, const float* __restrict__ ib1,
                 const float* __restrict__ iw2, const float* __restrict__ ib2,
                 const float* __restrict__ iw3, const float* __restrict__ ib3,
                 const float* __restrict__ vw1, const float* __restrict__ vb1,
                 const float* __restrict__ vw2, const float* __restrict__ vb2,
                 const float* __restrict__ vw3, const float* __restrict__ vb3,
                 const float* __restrict__ lw,  const float* __restrict__ lb,
                 float* __restrict__ out)
{
  __shared__ float w1s[Wn][W1S];          // 34.8 KB: w1s[o][k] row-major
  __shared__ float w2s[Wn][W2S];          // 67.6 KB: w2s[o][k] row-major
  __shared__ float xs_l[BT][Tn * Dn];     // 8 KB control path
  __shared__ float y_l[BT][YS];           // current state
  __shared__ float ys_l[BT][YS];          // stage input
  __shared__ float K_l[6][BT][KS];        // stage slopes
  __shared__ float h1_l[BT][HS];          // gap layout: [0..63] + [68..131]
  __shared__ float h2_l[BT][HS];
  __shared__ float lw_l[Hn];

  const int tid = threadIdx.x;
  const int b12 = tid & 3;          // L1/L2 batch row (tid<512)
  const int oL  = (tid >> 2) & 127; // L1/L2 output neuron (tid<512)
  const int pOL = oL + (oL >= 64 ? 4 : 0);  // gap-mapped phys index
  const int hf  = tid & 1;          // L3 k-half
  const int d   = (tid >> 1) & 7;   // L3 data-dim (vw3 row = tid>>1 = h3*8+d)
  const int h3  = tid >> 4;         // L3 hidden index, 0..63
  const int b0  = blockIdx.x * BT;

  const float b1r = vb1[oL];
  const float b2r = vb2[oL];
  const float b3r = vb3[tid >> 1];
  const float lb0 = lb[0];

  // ---- w3 half-row -> registers, ONCE (contiguous 256B per lane) ----
  float w3r[64];
  {
    const float4* p = (const float4*)(vw3 + tid * 64);  // (tid>>1)*128+(tid&1)*64
    #pragma unroll
    for (int i = 0; i < 16; ++i) {
      float4 v = p[i];
      w3r[4*i+0] = v.x; w3r[4*i+1] = v.y; w3r[4*i+2] = v.z; w3r[4*i+3] = v.w;
    }
  }

  // ---- stage w1/w2 row-major into LDS ----
  #pragma unroll
  for (int i = 0; i < 8; ++i) {           // 8192 f32 / 1024 threads
    const int e = i * NT + tid;           // e = o*64 + k
    w1s[e >> 6][e & 63] = vw1[e];
  }
  #pragma unroll
  for (int i = 0; i < 16; ++i) {          // 16384 f32 / 1024 threads
    const int e = i * NT + tid;           // e = o*128 + k
    const int k = e & 127;
    w2s[e >> 7][k] = vw2[e];              // w2 rows stay contiguous (no gap)
  }
  // ---- this block's xs rows (512 x float4 = 8 KB) ----
  if (tid < 512)
    ((float4*)&xs_l[0][0])[tid] = ((const float4*)(xs + b0 * Tn * Dn))[tid];
  if (tid < Hn) lw_l[tid] = lw[tid];
  __syncthreads();

  // ---- initial MLP (relu, relu, identity): y0 = mlp(xs[:,0]) ----
  if (tid < 512) {
    const int b = tid >> 7, oo = tid & 127;
    float acc = ib1[oo];
    #pragma unroll
    for (int k = 0; k < Dn; ++k) acc += iw1[oo * Dn + k] * xs_l[b][k];
    h1_l[b][oo + (oo >= 64 ? 4 : 0)] = fmaxf(acc, 0.f);
  }
  __syncthreads();
  if (tid < 512) {
    const int b = tid >> 7, oo = tid & 127;
    float acc = ib2[oo];
    const float4* wrow = (const float4*)(iw2 + oo * Wn);
    #pragma unroll
    for (int k4 = 0; k4 < 16; ++k4)
      acc += dot4(wrow[k4], *(const float4*)&h1_l[b][k4 * 4]);
    #pragma unroll
    for (int k4 = 0; k4 < 16; ++k4)
      acc += dot4(wrow[16 + k4], *(const float4*)&h1_l[b][GAP + k4 * 4]);
    h2_l[b][oo + (oo >= 64 ? 4 : 0)] = fmaxf(acc, 0.f);
  }
  __syncthreads();
  if (tid < BT * Hn) {
    const int b = tid >> 6, h = tid & (Hn - 1);
    float acc = ib3[h];
    const float4* wrow = (const float4*)(iw3 + h * Wn);
    #pragma unroll
    for (int k4 = 0; k4 < 16; ++k4)
      acc += dot4(wrow[k4], *(const float4*)&h2_l[b][k4 * 4]);
    #pragma unroll
    for (int k4 = 0; k4 < 16; ++k4)
      acc += dot4(wrow[16 + k4], *(const float4*)&h2_l[b][GAP + k4 * 4]);
    y_l[b][h]  = acc;
    ys_l[b][h] = acc;
  }
  __syncthreads();

  auto readout = [&](int t) {
    if (tid < BT * Hn) {
      const int wv = tid >> 6, h = tid & (Hn - 1);
      float p = lw_l[h] * y_l[wv][h];
      #pragma unroll
      for (int off = 32; off > 0; off >>= 1) p += __shfl_xor(p, off, 64);
      if (h == 0) out[(b0 + wv) * Tn + t] = fast_sigmoid(p + lb0);
    }
  };
  readout(0);

  // ---- 63 Tsit5 steps; per stage: L1 -> bar -> L2 -> bar -> L3+update -> bar
  #pragma unroll 1
  for (int t = 0; t < Tn - 1; ++t) {
    float dxr[BT];

    #pragma unroll 1
    for (int s = 0; s < 6; ++s) {
      if (s == 0) {
        #pragma unroll
        for (int b = 0; b < BT; ++b)
          dxr[b] = xs_l[b][(t + 1) * Dn + d] - xs_l[b][t * Dn + d];
      }

      // ---- vf layer 1 (tid<512): full 64-k dot, gap-mapped write ----
      if (tid < 512) {
        float acc = b1r;
        #pragma unroll
        for (int k4 = 0; k4 < 16; ++k4)
          acc += dot4(*(const float4*)&w1s[oL][k4 * 4],
                      *(const float4*)&ys_l[b12][k4 * 4]);
        h1_l[b12][pOL] = fast_softplus(acc);
      }
      __syncthreads();
      // ---- vf layer 2 (tid<512): full 128-k dot (front + gapped back) ----
      if (tid < 512) {
        float acc = b2r;
        #pragma unroll
        for (int k4 = 0; k4 < 16; ++k4)
          acc += dot4(*(const float4*)&w2s[oL][k4 * 4],
                      *(const float4*)&h1_l[b12][k4 * 4]);
        #pragma unroll
        for (int k4 = 0; k4 < 16; ++k4)
          acc += dot4(*(const float4*)&w2s[oL][64 + k4 * 4],
                      *(const float4*)&h1_l[b12][GAP + k4 * 4]);
        h2_l[b12][pOL] = fast_softplus(acc);
      }
      __syncthreads();
      // ---- vf layer 3 (all 1024): register w3, gap h2 reads, fused update
      {
        float a0 = 0.f, a1 = 0.f, a2 = 0.f, a3 = 0.f;
        const int kb = hf ? GAP : 0;      // disjoint bank-quads across hf
        #pragma unroll
        for (int c = 0; c < 16; ++c) {
          const int kk = kb + 4 * c;
          const float4 wv = *(const float4*)&w3r[4 * c];
          a0 += dot4(wv, *(const float4*)&h2_l[0][kk]);
          a1 += dot4(wv, *(const float4*)&h2_l[1][kk]);
          a2 += dot4(wv, *(const float4*)&h2_l[2][kk]);
          a3 += dot4(wv, *(const float4*)&h2_l[3][kk]);
        }
        // join k-halves (pair lane), tanh, einsum over d
        a0 += __shfl_xor(a0, 1, 64);
        a1 += __shfl_xor(a1, 1, 64);
        a2 += __shfl_xor(a2, 1, 64);
        a3 += __shfl_xor(a3, 1, 64);
        float p0 = fast_tanh(a0 + b3r) * dxr[0];
        float p1 = fast_tanh(a1 + b3r) * dxr[1];
        float p2 = fast_tanh(a2 + b3r) * dxr[2];
        float p3 = fast_tanh(a3 + b3r) * dxr[3];
        p0 += __shfl_xor(p0, 2, 64); p0 += __shfl_xor(p0, 4, 64); p0 += __shfl_xor(p0, 8, 64);
        p1 += __shfl_xor(p1, 2, 64); p1 += __shfl_xor(p1, 4, 64); p1 += __shfl_xor(p1, 8, 64);
        p2 += __shfl_xor(p2, 2, 64); p2 += __shfl_xor(p2, 4, 64); p2 += __shfl_xor(p2, 8, 64);
        p3 += __shfl_xor(p3, 2, 64); p3 += __shfl_xor(p3, 4, 64); p3 += __shfl_xor(p3, 8, 64);
        const int wl = tid & 15;
        if (wl < BT) {
          const float kv = (wl == 0) ? p0 : (wl == 1) ? p1 : (wl == 2) ? p2 : p3;
          K_l[s][wl][h3] = kv;
          float v = y_l[wl][h3];
          if (s == 0)      v += A21 * kv;
          else if (s == 1) v += A31 * K_l[0][wl][h3] + A32 * kv;
          else if (s == 2) v += A41 * K_l[0][wl][h3] + A42 * K_l[1][wl][h3] + A43 * kv;
          else if (s == 3) v += A51 * K_l[0][wl][h3] + A52 * K_l[1][wl][h3]
                              + A53 * K_l[2][wl][h3] + A54 * kv;
          else if (s == 4) v += A61 * K_l[0][wl][h3] + A62 * K_l[1][wl][h3]
                              + A63 * K_l[2][wl][h3] + A64 * K_l[3][wl][h3] + A65 * kv;
          else             v += Bc1 * K_l[0][wl][h3] + Bc2 * K_l[1][wl][h3]
                              + Bc3 * K_l[2][wl][h3] + Bc4 * K_l[3][wl][h3]
                              + Bc5 * K_l[4][wl][h3] + Bc6 * kv;
          if (s < 5) {
            ys_l[wl][h3] = v;
          } else {
            y_l[wl][h3]  = v;
            ys_l[wl][h3] = v;
          }
        }
      }
      __syncthreads();
    }
    readout(t + 1);
  }
}

extern "C" void kernel_launch(void* const* d_in, const int* in_sizes, int n_in,
                              void* d_out, int out_size, void* d_ws, size_t ws_size,
                              hipStream_t stream) {
  const float* xs  = (const float*)d_in[1];
  const float* iw1 = (const float*)d_in[2];
  const float* ib1 = (const float*)d_in[3];
  const float* iw2 = (const float*)d_in[4];
  const float* ib2 = (const float*)d_in[5];
  const float* iw3 = (const float*)d_in[6];
  const float* ib3 = (const float*)d_in[7];
  const float* vw1 = (const float*)d_in[8];
  const float* vb1 = (const float*)d_in[9];
  const float* vw2 = (const float*)d_in[10];
  const float* vb2 = (const float*)d_in[11];
  const float* vw3 = (const float*)d_in[12];
  const float* vb3 = (const float*)d_in[13];
  const float* lw  = (const float*)d_in[14];
  const float* lb  = (const float*)d_in[15];
  float* out = (float*)d_out;

  ncde_kernel<<<Bb / BT, NT, 0, stream>>>(xs, iw1, ib1, iw2, ib2, iw3, ib3,
                                          vw1, vb1, vw2, vb2, vw3, vb3, lw, lb, out);
}